// Round 14
// baseline (118.738 us; speedup 1.0000x reference)
//
#include <hip/hip_runtime.h>

#define D_ 64
#define H_ 128
#define W_ 128
#define VOL (D_*H_*W_)   // 1048576 = 1<<20
#define NF 4             // {pred,target} x {b0,b1}
#define LARGEF 1e8f
#define SW(r,c) (((r) << 7) + ((c) ^ ((r) & 31)))   // bank-conflict-free both axes

__device__ __forceinline__ bool maskv(float v, int which) {
  // which==0: pred mask = sigmoid(v)>0.5 <=> v>0 ; which==1: target != 0
  return which ? (v != 0.0f) : (v > 0.0f);
}

// ---- surface extraction, 4 voxels/thread: 5 float4 + 2 scalar loads instead
// of 28 scalar; uchar4 coalesced store. Massive TLP hides latency.
__global__ __launch_bounds__(256) void k_init(const float* __restrict__ pred,
                                              const float* __restrict__ targ,
                                              unsigned char* __restrict__ surf,
                                              double* __restrict__ acc) {
  int idx = blockIdx.x * 256 + threadIdx.x;          // [0, NF*VOL/4)
  if (idx < 3) acc[idx] = 0.0;                       // acc[0],acc[1],counter slot
  int f = idx >> 18;                                 // VOL/4 = 2^18
  int q = idx & 262143;
  int which = f & 1;
  const float* __restrict__ src = (which ? targ : pred) + ((size_t)(f >> 1) << 20);
  const float4* __restrict__ s4 = (const float4*)src;
  int v = q << 2;
  int z = v >> 14, y = (v >> 7) & 127, x = v & 127;  // x multiple of 4
  float4 c = s4[q];
  bool m0 = maskv(c.x, which), m1 = maskv(c.y, which);
  bool m2 = maskv(c.z, which), m3 = maskv(c.w, which);
  bool ym0=false, ym1=false, ym2=false, ym3=false;
  bool yp0=false, yp1=false, yp2=false, yp3=false;
  bool zm0=false, zm1=false, zm2=false, zm3=false;
  bool zp0=false, zp1=false, zp2=false, zp3=false;
  if (y > 0)   { float4 t = s4[q - 32];   ym0=maskv(t.x,which); ym1=maskv(t.y,which); ym2=maskv(t.z,which); ym3=maskv(t.w,which); }
  if (y < 127) { float4 t = s4[q + 32];   yp0=maskv(t.x,which); yp1=maskv(t.y,which); yp2=maskv(t.z,which); yp3=maskv(t.w,which); }
  if (z > 0)   { float4 t = s4[q - 4096]; zm0=maskv(t.x,which); zm1=maskv(t.y,which); zm2=maskv(t.z,which); zm3=maskv(t.w,which); }
  if (z < 63)  { float4 t = s4[q + 4096]; zp0=maskv(t.x,which); zp1=maskv(t.y,which); zp2=maskv(t.z,which); zp3=maskv(t.w,which); }
  bool lm = (x > 0)   ? maskv(src[v - 1], which) : false;
  bool rm = (x < 124) ? maskv(src[v + 4], which) : false;
  bool e0 = m0 && lm && m1 && ym0 && yp0 && zm0 && zp0;
  bool e1 = m1 && m0 && m2 && ym1 && yp1 && zm1 && zp1;
  bool e2 = m2 && m1 && m3 && ym2 && yp2 && zm2 && zp2;
  bool e3 = m3 && m2 && rm && ym3 && yp3 && zm3 && zp3;
  uchar4 o;
  o.x = (unsigned char)(m0 && !e0);
  o.y = (unsigned char)(m1 && !e1);
  o.z = (unsigned char)(m2 && !e2);
  o.w = (unsigned char)(m3 && !e3);
  ((uchar4*)surf)[idx] = o;                          // surface = m && !eroded
}

// ---- z two-scan EDT over surface bytes -> u8 z-dist (255 = no surface).
// One thread per (f,y,x) column; unroll 16 keeps many loads in flight.
__global__ __launch_bounds__(256) void k_zscan(const unsigned char* __restrict__ surf,
                                               unsigned char* __restrict__ zdist) {
  __shared__ unsigned short fwd[D_][256];            // u16: 2-way banks = free
  int g = blockIdx.x * 256 + threadIdx.x;            // 65536 columns
  int f = g >> 14, yx = g & 16383;
  const unsigned char* s = surf + (f << 20) + yx;
  unsigned char* o = zdist + (f << 20) + yx;
  int d = 255;
  #pragma unroll 16
  for (int z = 0; z < D_; ++z) {
    d = s[z << 14] ? 0 : min(d + 1, 255);            // fv in {255} U [0,63]
    fwd[z][threadIdx.x] = (unsigned short)d;
  }
  int dd = 255;                                      // column thread-private: no sync
  #pragma unroll 8
  for (int z = D_ - 1; z >= 0; --z) {
    int fv = fwd[z][threadIdx.x];
    dd = (fv == 0) ? 0 : min(dd + 1, 255);
    o[z << 14] = (unsigned char)min(fv, dd);         // in {255} U [0,63]
  }
}

// ---- fused y+x EDT on one (f,z) slab in 64KB swizzled LDS, with EXACT
// window pruning: best[i] <= t[i] (the j=i candidate), so only j with
// (i-j)^2 < t[i] can win -> wave-uniform window of ~2*sqrt(tmax)+16.
// floor(sqrtf(exact int)) never under-estimates; excluded ties can't change
// the min value. Candidates kept are computed bit-identically to the full loop.
__global__ __launch_bounds__(1024) void k_edt_yx(const unsigned char* __restrict__ zdist,
                                                 float* __restrict__ dist) {
  __shared__ float tile[128 * 128];                  // exactly 64 KB
  int f = blockIdx.y, z = blockIdx.x;
  const uchar4* __restrict__ z4 = (const uchar4*)(zdist + (f << 20) + (z << 14));
  float* dbase = dist + (f << 20) + (z << 14);
  #pragma unroll
  for (int e4 = threadIdx.x, i = 0; i < 4; ++i, e4 += 1024) {  // uchar4 stage
    int r = e4 >> 5, c0 = (e4 & 31) << 2;            // r=y, c0=x (mult of 4)
    uchar4 bb = z4[e4];
    float r2 = (float)(r * r);
    tile[SW(r, c0 + 0)] = ((bb.x == 255) ? LARGEF : (float)(bb.x * bb.x)) + r2;
    tile[SW(r, c0 + 1)] = ((bb.y == 255) ? LARGEF : (float)(bb.y * bb.y)) + r2;
    tile[SW(r, c0 + 2)] = ((bb.z == 255) ? LARGEF : (float)(bb.z * bb.z)) + r2;
    tile[SW(r, c0 + 3)] = ((bb.w == 255) ? LARGEF : (float)(bb.w * bb.w)) + r2;
  }
  __syncthreads();
  const int R = 16;
  int tp = threadIdx.x & 127, tw = threadIdx.x >> 7; // tw in [0,8), wave-uniform
  float best[R], fi[R];
  float fb = (float)(tw * R);
  // ---- y-pass: tp = x column; outputs i in [16tw,16tw+16)
  float tmax = 0.0f;
  #pragma unroll
  for (int u = 0; u < R; ++u) {
    fi[u] = fb + (float)u; best[u] = 3.0e8f;
    float tv = tile[SW(tw * R + u, tp)] - fi[u] * fi[u];  // = zd^2(i,tp), exact
    tmax = fmaxf(tmax, tv);
  }
  #pragma unroll
  for (int o = 1; o < 64; o <<= 1) tmax = fmaxf(tmax, __shfl_xor(tmax, o));
  int rad = (int)sqrtf(tmax);
  int jlo = max(0, tw * R - rad), jhi = min(H_ - 1, tw * R + (R - 1) + rad);
  for (int j = jlo; j <= jhi; ++j) {
    float t = tile[SW(j, tp)];                       // zd^2 + j^2
    float m2j = -2.0f * (float)j;
    #pragma unroll
    for (int u = 0; u < R; ++u)
      best[u] = fminf(best[u], __builtin_fmaf(m2j, fi[u], t));
  }
  __syncthreads();                                   // all rows read before overwrite
  float fx2 = (float)(tp * tp);                      // +x^2 fold for the x-pass
  #pragma unroll
  for (int u = 0; u < R; ++u)
    tile[SW(tw * R + u, tp)] = best[u] + fi[u] * fi[u] + fx2;  // yEDT(i,tp)+tp^2
  __syncthreads();
  // ---- x-pass: tp = y line; outputs xi in [16tw,16tw+16).
  // tile[SW(tp, j)] = yEDT(tp, j) + j^2 -> the +j^2 fold is exactly the
  // candidate's term; no unfold subtraction (round-10 bug).
  tmax = 0.0f;
  #pragma unroll
  for (int u = 0; u < R; ++u) {
    best[u] = 3.0e8f;
    float tv = tile[SW(tp, tw * R + u)] - fi[u] * fi[u];  // = yEDT(tp,i), exact
    tmax = fmaxf(tmax, tv);
  }
  #pragma unroll
  for (int o = 1; o < 64; o <<= 1) tmax = fmaxf(tmax, __shfl_xor(tmax, o));
  rad = (int)sqrtf(tmax);
  jlo = max(0, tw * R - rad); jhi = min(W_ - 1, tw * R + (R - 1) + rad);
  for (int j = jlo; j <= jhi; ++j) {
    float t = tile[SW(tp, j)];                       // yEDT + j^2
    float m2j = -2.0f * (float)j;
    #pragma unroll
    for (int u = 0; u < R; ++u)
      best[u] = fminf(best[u], __builtin_fmaf(m2j, fi[u], t));
  }
  __syncthreads();
  #pragma unroll
  for (int u = 0; u < R; ++u)
    tile[SW(tp, tw * R + u)] = sqrtf(best[u] + fi[u] * fi[u]);
  __syncthreads();
  for (int e = threadIdx.x; e < 16384; e += 1024)    // coalesced writeback
    dbase[e] = tile[SW(e >> 7, e & 127)];
}

// ---- smooth-L1 + last-block finalize (fused k_final: saves a launch).
// Per-block partial -> atomicAdd(acc[b]); 512th block computes out[0].
__global__ __launch_bounds__(256) void k_reduce(const float* __restrict__ dist,
                                               double* __restrict__ acc,
                                               float* __restrict__ out) {
  int b = blockIdx.y;
  const float4* dp = (const float4*)(dist + ((size_t)(b * 2 + 0) << 20));
  const float4* dt = (const float4*)(dist + ((size_t)(b * 2 + 1) << 20));
  double s = 0.0;
  for (int v = blockIdx.x * 256 + threadIdx.x; v < VOL / 4; v += gridDim.x * 256) {
    float4 a = dp[v], c = dt[v];
    float d0 = a.x - c.x, d1 = a.y - c.y, d2v = a.z - c.z, d3 = a.w - c.w;
    float a0 = fabsf(d0), a1 = fabsf(d1), a2 = fabsf(d2v), a3 = fabsf(d3);
    s += (double)(a0 < 1.0f ? 0.5f * d0 * d0 : a0 - 0.5f);
    s += (double)(a1 < 1.0f ? 0.5f * d1 * d1 : a1 - 0.5f);
    s += (double)(a2 < 1.0f ? 0.5f * d2v * d2v : a2 - 0.5f);
    s += (double)(a3 < 1.0f ? 0.5f * d3 * d3 : a3 - 0.5f);
  }
  for (int o = 32; o > 0; o >>= 1) s += __shfl_down(s, o);
  __shared__ double wsum[4];
  if ((threadIdx.x & 63) == 0) wsum[threadIdx.x >> 6] = s;
  __syncthreads();
  if (threadIdx.x == 0) {
    atomicAdd(&acc[b], wsum[0] + wsum[1] + wsum[2] + wsum[3]);
    __threadfence();                                 // release partial before ticket
    unsigned* ctr = (unsigned*)&acc[2];              // zeroed by k_init
    unsigned done = atomicAdd(ctr, 1u);
    if (done == gridDim.x * gridDim.y - 1) {         // last block: all adds visible
      __threadfence();                               // acquire
      out[0] = (float)(0.5 * (acc[0] / (double)VOL + acc[1] / (double)VOL));
    }
  }
}

extern "C" void kernel_launch(void* const* d_in, const int* in_sizes, int n_in,
                              void* d_out, int out_size, void* d_ws, size_t ws_size,
                              hipStream_t stream) {
  const float* pred = (const float*)d_in[0];
  const float* targ = (const float*)d_in[1];
  unsigned char* surf  = (unsigned char*)d_ws;                       // 4 MB
  unsigned char* zdist = (unsigned char*)d_ws + ((size_t)NF << 20);  // 4 MB
  float*  dist = (float*)((char*)d_ws + ((size_t)NF << 21));         // 16 MB
  double* acc  = (double*)((char*)d_ws + ((size_t)NF << 21) + ((size_t)NF * VOL * 4));
  float*  out  = (float*)d_out;

  k_init  <<<NF * VOL / 4 / 256, 256, 0, stream>>>(pred, targ, surf, acc);
  k_zscan <<<NF * H_ * W_ / 256, 256, 0, stream>>>(surf, zdist);
  k_edt_yx<<<dim3(D_, NF), 1024, 0, stream>>>(zdist, dist);
  k_reduce<<<dim3(256, 2), 256, 0, stream>>>(dist, acc, out);
}

// Round 15
// 115.504 us; speedup vs baseline: 1.0280x; 1.0280x over previous
//
#include <hip/hip_runtime.h>

#define D_ 64
#define H_ 128
#define W_ 128
#define VOL (D_*H_*W_)   // 1048576 = 1<<20
#define NF 4             // {pred,target} x {b0,b1}
#define LARGEF 1e8f
#define SW(r,c) (((r) << 7) + ((c) ^ ((r) & 31)))   // bank-conflict-free both axes

__device__ __forceinline__ bool maskv(float v, int which) {
  // which==0: pred mask = sigmoid(v)>0.5 <=> v>0 ; which==1: target != 0
  return which ? (v != 0.0f) : (v > 0.0f);
}

// ---- surface extraction, 4 voxels/thread: 5 float4 + 2 scalar loads instead
// of 28 scalar; uchar4 coalesced store. Massive TLP hides latency.
__global__ __launch_bounds__(256) void k_init(const float* __restrict__ pred,
                                              const float* __restrict__ targ,
                                              unsigned char* __restrict__ surf,
                                              double* __restrict__ acc) {
  int idx = blockIdx.x * 256 + threadIdx.x;          // [0, NF*VOL/4)
  if (idx < 3) acc[idx] = 0.0;                       // acc[0],acc[1],counter slot
  int f = idx >> 18;                                 // VOL/4 = 2^18
  int q = idx & 262143;
  int which = f & 1;
  const float* __restrict__ src = (which ? targ : pred) + ((size_t)(f >> 1) << 20);
  const float4* __restrict__ s4 = (const float4*)src;
  int v = q << 2;
  int z = v >> 14, y = (v >> 7) & 127, x = v & 127;  // x multiple of 4
  float4 c = s4[q];
  bool m0 = maskv(c.x, which), m1 = maskv(c.y, which);
  bool m2 = maskv(c.z, which), m3 = maskv(c.w, which);
  bool ym0=false, ym1=false, ym2=false, ym3=false;
  bool yp0=false, yp1=false, yp2=false, yp3=false;
  bool zm0=false, zm1=false, zm2=false, zm3=false;
  bool zp0=false, zp1=false, zp2=false, zp3=false;
  if (y > 0)   { float4 t = s4[q - 32];   ym0=maskv(t.x,which); ym1=maskv(t.y,which); ym2=maskv(t.z,which); ym3=maskv(t.w,which); }
  if (y < 127) { float4 t = s4[q + 32];   yp0=maskv(t.x,which); yp1=maskv(t.y,which); yp2=maskv(t.z,which); yp3=maskv(t.w,which); }
  if (z > 0)   { float4 t = s4[q - 4096]; zm0=maskv(t.x,which); zm1=maskv(t.y,which); zm2=maskv(t.z,which); zm3=maskv(t.w,which); }
  if (z < 63)  { float4 t = s4[q + 4096]; zp0=maskv(t.x,which); zp1=maskv(t.y,which); zp2=maskv(t.z,which); zp3=maskv(t.w,which); }
  bool lm = (x > 0)   ? maskv(src[v - 1], which) : false;
  bool rm = (x < 124) ? maskv(src[v + 4], which) : false;
  bool e0 = m0 && lm && m1 && ym0 && yp0 && zm0 && zp0;
  bool e1 = m1 && m0 && m2 && ym1 && yp1 && zm1 && zp1;
  bool e2 = m2 && m1 && m3 && ym2 && yp2 && zm2 && zp2;
  bool e3 = m3 && m2 && rm && ym3 && yp3 && zm3 && zp3;
  uchar4 o;
  o.x = (unsigned char)(m0 && !e0);
  o.y = (unsigned char)(m1 && !e1);
  o.z = (unsigned char)(m2 && !e2);
  o.w = (unsigned char)(m3 && !e3);
  ((uchar4*)surf)[idx] = o;                          // surface = m && !eroded
}

// ---- z two-scan EDT over surface bytes -> u8 z-dist (255 = no surface).
// One thread per (f,y,x) column; unroll 16 keeps many loads in flight.
__global__ __launch_bounds__(256) void k_zscan(const unsigned char* __restrict__ surf,
                                               unsigned char* __restrict__ zdist) {
  __shared__ unsigned short fwd[D_][256];            // u16: 2-way banks = free
  int g = blockIdx.x * 256 + threadIdx.x;            // 65536 columns
  int f = g >> 14, yx = g & 16383;
  const unsigned char* s = surf + (f << 20) + yx;
  unsigned char* o = zdist + (f << 20) + yx;
  int d = 255;
  #pragma unroll 16
  for (int z = 0; z < D_; ++z) {
    d = s[z << 14] ? 0 : min(d + 1, 255);            // fv in {255} U [0,63]
    fwd[z][threadIdx.x] = (unsigned short)d;
  }
  int dd = 255;                                      // column thread-private: no sync
  #pragma unroll 8
  for (int z = D_ - 1; z >= 0; --z) {
    int fv = fwd[z][threadIdx.x];
    dd = (fv == 0) ? 0 : min(dd + 1, 255);
    o[z << 14] = (unsigned char)min(fv, dd);         // in {255} U [0,63]
  }
}

// ---- fused y+x EDT on one (f,z) slab in 64KB swizzled LDS, with EXACT
// window pruning (best[i] <= j=i candidate). Outputs EXACT u16 squared
// distances (<= 3*127^2 = 48387; 65535 = sentinel for empty field) via
// direct reg->global 16B stores — no final LDS round-trip.
// Stage is SCALAR byte loads: each lane writes one swizzled float (32 distinct
// banks/wave). R14's uchar4 stage made 4 consecutive columns per lane ->
// 8-way bank conflict -> regression. Do not re-vectorize the stage.
__global__ __launch_bounds__(1024) void k_edt_yx(const unsigned char* __restrict__ zdist,
                                                 unsigned short* __restrict__ d2s) {
  __shared__ float tile[128 * 128];                  // exactly 64 KB
  int f = blockIdx.y, z = blockIdx.x;
  const unsigned char* zsrc = zdist + (f << 20) + (z << 14);
  for (int e = threadIdx.x; e < 16384; e += 1024) {  // stage: decode + y-fold (+y^2)
    int r = e >> 7, c = e & 127;                     // r=y, c=x
    int b = zsrc[e];
    float v = (b == 255) ? LARGEF : (float)(b * b);
    tile[SW(r, c)] = v + (float)(r * r);             // tile[y][x] = zd^2 + y^2
  }
  __syncthreads();
  const int R = 16;
  int tp = threadIdx.x & 127, tw = threadIdx.x >> 7; // tw in [0,8), wave-uniform
  float best[R], fi[R];
  float fb = (float)(tw * R);
  // ---- y-pass: tp = x column; outputs i in [16tw,16tw+16)
  float tmax = 0.0f;
  #pragma unroll
  for (int u = 0; u < R; ++u) {
    fi[u] = fb + (float)u; best[u] = 3.0e8f;
    float tv = tile[SW(tw * R + u, tp)] - fi[u] * fi[u];  // = zd^2(i,tp), exact
    tmax = fmaxf(tmax, tv);
  }
  #pragma unroll
  for (int o = 1; o < 64; o <<= 1) tmax = fmaxf(tmax, __shfl_xor(tmax, o));
  int rad = (int)sqrtf(tmax);
  int jlo = max(0, tw * R - rad), jhi = min(H_ - 1, tw * R + (R - 1) + rad);
  for (int j = jlo; j <= jhi; ++j) {
    float t = tile[SW(j, tp)];                       // zd^2 + j^2
    float m2j = -2.0f * (float)j;
    #pragma unroll
    for (int u = 0; u < R; ++u)
      best[u] = fminf(best[u], __builtin_fmaf(m2j, fi[u], t));
  }
  __syncthreads();                                   // all rows read before overwrite
  float fx2 = (float)(tp * tp);                      // +x^2 fold for the x-pass
  #pragma unroll
  for (int u = 0; u < R; ++u)
    tile[SW(tw * R + u, tp)] = best[u] + fi[u] * fi[u] + fx2;  // yEDT(i,tp)+tp^2
  __syncthreads();
  // ---- x-pass: tp = y line; outputs xi in [16tw,16tw+16).
  // tile[SW(tp, j)] = yEDT(tp, j) + j^2 -> fold IS the candidate's +j^2 term.
  tmax = 0.0f;
  #pragma unroll
  for (int u = 0; u < R; ++u) {
    best[u] = 3.0e8f;
    float tv = tile[SW(tp, tw * R + u)] - fi[u] * fi[u];  // = yEDT(tp,i), exact
    tmax = fmaxf(tmax, tv);
  }
  #pragma unroll
  for (int o = 1; o < 64; o <<= 1) tmax = fmaxf(tmax, __shfl_xor(tmax, o));
  rad = (int)sqrtf(tmax);
  jlo = max(0, tw * R - rad); jhi = min(W_ - 1, tw * R + (R - 1) + rad);
  for (int j = jlo; j <= jhi; ++j) {
    float t = tile[SW(tp, j)];                       // yEDT + j^2
    float m2j = -2.0f * (float)j;
    #pragma unroll
    for (int u = 0; u < R; ++u)
      best[u] = fminf(best[u], __builtin_fmaf(m2j, fi[u], t));
  }
  // ---- direct u16 writeback: 16 consecutive voxels/thread, 32B aligned.
  unsigned pk[8];
  #pragma unroll
  for (int p = 0; p < 8; ++p) {
    float dlo = best[2*p]     + fi[2*p]     * fi[2*p];      // exact int <= 48387
    float dhi = best[2*p + 1] + fi[2*p + 1] * fi[2*p + 1];  // or ~1e8 (empty field)
    unsigned lo = (dlo > 65504.f) ? 65535u : (unsigned)dlo;
    unsigned hi = (dhi > 65504.f) ? 65535u : (unsigned)dhi;
    pk[p] = lo | (hi << 16);
  }
  uint4* ob = (uint4*)(d2s + (f << 20) + (z << 14) + (tp << 7) + tw * R);
  ob[0] = make_uint4(pk[0], pk[1], pk[2], pk[3]);
  ob[1] = make_uint4(pk[4], pk[5], pk[6], pk[7]);
}

// ---- smooth-L1 over u16 d2 (decode -> sqrtf, bit-identical to f32 path),
// last-block finalize writes out[0]. Double accumulation.
__global__ __launch_bounds__(256) void k_reduce(const unsigned short* __restrict__ d2s,
                                               double* __restrict__ acc,
                                               float* __restrict__ out) {
  int b = blockIdx.y;
  const uint4* dp = (const uint4*)(d2s + ((size_t)(b * 2 + 0) << 20));
  const uint4* dt = (const uint4*)(d2s + ((size_t)(b * 2 + 1) << 20));
  double s = 0.0;
  for (int v = blockIdx.x * 256 + threadIdx.x; v < VOL / 8; v += gridDim.x * 256) {
    uint4 A = dp[v], C = dt[v];
    unsigned aw[4] = {A.x, A.y, A.z, A.w};
    unsigned cw[4] = {C.x, C.y, C.z, C.w};
    #pragma unroll
    for (int k = 0; k < 4; ++k) {
      unsigned a0 = aw[k] & 0xFFFFu, a1 = aw[k] >> 16;
      unsigned c0 = cw[k] & 0xFFFFu, c1 = cw[k] >> 16;
      float da0 = sqrtf(a0 == 65535u ? LARGEF : (float)a0);
      float da1 = sqrtf(a1 == 65535u ? LARGEF : (float)a1);
      float dc0 = sqrtf(c0 == 65535u ? LARGEF : (float)c0);
      float dc1 = sqrtf(c1 == 65535u ? LARGEF : (float)c1);
      float d0 = da0 - dc0, d1 = da1 - dc1;
      float b0 = fabsf(d0), b1 = fabsf(d1);
      s += (double)(b0 < 1.0f ? 0.5f * d0 * d0 : b0 - 0.5f);
      s += (double)(b1 < 1.0f ? 0.5f * d1 * d1 : b1 - 0.5f);
    }
  }
  for (int o = 32; o > 0; o >>= 1) s += __shfl_down(s, o);
  __shared__ double wsum[4];
  if ((threadIdx.x & 63) == 0) wsum[threadIdx.x >> 6] = s;
  __syncthreads();
  if (threadIdx.x == 0) {
    atomicAdd(&acc[b], wsum[0] + wsum[1] + wsum[2] + wsum[3]);
    __threadfence();                                 // release partial before ticket
    unsigned* ctr = (unsigned*)&acc[2];              // zeroed by k_init
    unsigned done = atomicAdd(ctr, 1u);
    if (done == gridDim.x * gridDim.y - 1) {         // last block: all adds visible
      __threadfence();                               // acquire
      out[0] = (float)(0.5 * (acc[0] / (double)VOL + acc[1] / (double)VOL));
    }
  }
}

extern "C" void kernel_launch(void* const* d_in, const int* in_sizes, int n_in,
                              void* d_out, int out_size, void* d_ws, size_t ws_size,
                              hipStream_t stream) {
  const float* pred = (const float*)d_in[0];
  const float* targ = (const float*)d_in[1];
  unsigned char*  surf  = (unsigned char*)d_ws;                       // 4 MB
  unsigned char*  zdist = (unsigned char*)d_ws + ((size_t)NF << 20);  // 4 MB
  unsigned short* d2s   = (unsigned short*)((char*)d_ws + ((size_t)NF << 21)); // 8 MB
  double* acc = (double*)((char*)d_ws + ((size_t)NF << 21) + ((size_t)NF * VOL * 2));
  float*  out = (float*)d_out;

  k_init  <<<NF * VOL / 4 / 256, 256, 0, stream>>>(pred, targ, surf, acc);
  k_zscan <<<NF * H_ * W_ / 256, 256, 0, stream>>>(surf, zdist);
  k_edt_yx<<<dim3(D_, NF), 1024, 0, stream>>>(zdist, d2s);
  k_reduce<<<dim3(256, 2), 256, 0, stream>>>(d2s, acc, out);
}